// Round 3
// baseline (81.509 us; speedup 1.0000x reference)
//
#include <hip/hip_runtime.h>
#include <hip/hip_bf16.h>

// RisingTideAttentionV2: out[m,:] = norm( exp(-||x_m - p_n|| / efft_n) ) @ V
// M=16384, N=4096, D=128. d2 = x2[m] + p2[n] - 2*dot(x_m,p_n). NEURON_SCALE=0.05125
//
// Inverted structure: block = (n-tile 128) x (m-chunk 512). P fragments are
// loop-invariant in registers; X (bf16) streams through a double-buffered LDS
// subtile via global_load_lds with counted vmcnt (raw barriers). Weights all
// underflow to exact 0.0f for this data; the exact nonzero path (PV via MFMA +
// atomicAdd into pre-zeroed d_out) is kept for generality. rsum partials go to
// scratch and a small normalize kernel combines + scales.

typedef __attribute__((ext_vector_type(8))) short short8;
typedef __attribute__((ext_vector_type(4))) float f32x4;

#define MTOT 16384
#define NTOT 4096
#define DD   128

__device__ __forceinline__ short f2bf(float f) {
    unsigned u = __float_as_uint(f);
    unsigned r = (u + 0x7fffu + ((u >> 16) & 1u)) >> 16;
    return (short)r;
}

// ---------------- prep: Xb bf16 + x2, Pb bf16 + p2/cg, Vt bf16, zero out ----
// blocks 0..511: X rows (32/block). 512..639: pos/val/temp (32 n/block).
// 640..1151: zero d_out (16 KB/block).
__global__ __launch_bounds__(256) void tide_prep(
    const float* __restrict__ x, const float* __restrict__ pos,
    const float* __restrict__ val, const float* __restrict__ temp,
    short* __restrict__ Xb, float* __restrict__ x2g,
    short* __restrict__ Pb, float* __restrict__ p2g, float* __restrict__ cg,
    short* __restrict__ Vt, float* __restrict__ outz)
{
    const int bid = blockIdx.x, tid = threadIdx.x;
    if (bid < 512) {
        const int r = tid >> 3, sub = tid & 7;
        const int row = bid * 32 + r;
        const float* src = x + (size_t)row * DD + sub * 16;
        f32x4 a0 = ((const f32x4*)src)[0];
        f32x4 a1 = ((const f32x4*)src)[1];
        f32x4 a2 = ((const f32x4*)src)[2];
        f32x4 a3 = ((const f32x4*)src)[3];
        short8 h0, h1;
        h0[0]=f2bf(a0[0]); h0[1]=f2bf(a0[1]); h0[2]=f2bf(a0[2]); h0[3]=f2bf(a0[3]);
        h0[4]=f2bf(a1[0]); h0[5]=f2bf(a1[1]); h0[6]=f2bf(a1[2]); h0[7]=f2bf(a1[3]);
        h1[0]=f2bf(a2[0]); h1[1]=f2bf(a2[1]); h1[2]=f2bf(a2[2]); h1[3]=f2bf(a2[3]);
        h1[4]=f2bf(a3[0]); h1[5]=f2bf(a3[1]); h1[6]=f2bf(a3[2]); h1[7]=f2bf(a3[3]);
        *(short8*)(Xb + (size_t)row * DD + sub * 16)     = h0;
        *(short8*)(Xb + (size_t)row * DD + sub * 16 + 8) = h1;
        float s = a0[0]*a0[0]+a0[1]*a0[1]+a0[2]*a0[2]+a0[3]*a0[3]
                + a1[0]*a1[0]+a1[1]*a1[1]+a1[2]*a1[2]+a1[3]*a1[3]
                + a2[0]*a2[0]+a2[1]*a2[1]+a2[2]*a2[2]+a2[3]*a2[3]
                + a3[0]*a3[0]+a3[1]*a3[1]+a3[2]*a3[2]+a3[3]*a3[3];
        s += __shfl_xor(s, 1); s += __shfl_xor(s, 2); s += __shfl_xor(s, 4);
        if (sub == 0) x2g[row] = s;
    } else if (bid < 640) {
        __shared__ short ldsv[32][132];
        const int r = tid >> 3, sub = tid & 7;
        const int n0 = (bid - 512) * 32;
        const int n = n0 + r;
        // P + p2 + cg
        const float* ps = pos + (size_t)n * DD + sub * 16;
        f32x4 a0 = ((const f32x4*)ps)[0];
        f32x4 a1 = ((const f32x4*)ps)[1];
        f32x4 a2 = ((const f32x4*)ps)[2];
        f32x4 a3 = ((const f32x4*)ps)[3];
        short8 h0, h1;
        h0[0]=f2bf(a0[0]); h0[1]=f2bf(a0[1]); h0[2]=f2bf(a0[2]); h0[3]=f2bf(a0[3]);
        h0[4]=f2bf(a1[0]); h0[5]=f2bf(a1[1]); h0[6]=f2bf(a1[2]); h0[7]=f2bf(a1[3]);
        h1[0]=f2bf(a2[0]); h1[1]=f2bf(a2[1]); h1[2]=f2bf(a2[2]); h1[3]=f2bf(a2[3]);
        h1[4]=f2bf(a3[0]); h1[5]=f2bf(a3[1]); h1[6]=f2bf(a3[2]); h1[7]=f2bf(a3[3]);
        *(short8*)(Pb + (size_t)n * DD + sub * 16)     = h0;
        *(short8*)(Pb + (size_t)n * DD + sub * 16 + 8) = h1;
        float s = a0[0]*a0[0]+a0[1]*a0[1]+a0[2]*a0[2]+a0[3]*a0[3]
                + a1[0]*a1[0]+a1[1]*a1[1]+a1[2]*a1[2]+a1[3]*a1[3]
                + a2[0]*a2[0]+a2[1]*a2[1]+a2[2]*a2[2]+a2[3]*a2[3]
                + a3[0]*a3[0]+a3[1]*a3[1]+a3[2]*a3[2]+a3[3]*a3[3];
        s += __shfl_xor(s, 1); s += __shfl_xor(s, 2); s += __shfl_xor(s, 4);
        if (sub == 0) {
            p2g[n] = s;
            float efft = (fabsf(temp[n]) + 0.1f) * 0.05125f;
            cg[n] = -1.4426950408889634f / efft;  // exp(-d/efft)=exp2(d*cg)
        }
        // V: convert -> LDS -> transposed store
        const float* vs = val + (size_t)n * DD + sub * 16;
        f32x4 b0 = ((const f32x4*)vs)[0];
        f32x4 b1 = ((const f32x4*)vs)[1];
        f32x4 b2 = ((const f32x4*)vs)[2];
        f32x4 b3 = ((const f32x4*)vs)[3];
        short* dstv = &ldsv[r][sub * 16];
        dstv[0]=f2bf(b0[0]); dstv[1]=f2bf(b0[1]); dstv[2]=f2bf(b0[2]); dstv[3]=f2bf(b0[3]);
        dstv[4]=f2bf(b1[0]); dstv[5]=f2bf(b1[1]); dstv[6]=f2bf(b1[2]); dstv[7]=f2bf(b1[3]);
        dstv[8]=f2bf(b2[0]); dstv[9]=f2bf(b2[1]); dstv[10]=f2bf(b2[2]); dstv[11]=f2bf(b2[3]);
        dstv[12]=f2bf(b3[0]); dstv[13]=f2bf(b3[1]); dstv[14]=f2bf(b3[2]); dstv[15]=f2bf(b3[3]);
        __syncthreads();
        const int d = tid >> 1, half = tid & 1;
        short8 t0, t1;
        #pragma unroll
        for (int j = 0; j < 8; ++j) t0[j] = ldsv[half * 16 + j][d];
        #pragma unroll
        for (int j = 0; j < 8; ++j) t1[j] = ldsv[half * 16 + 8 + j][d];
        *(short8*)(Vt + (size_t)d * NTOT + n0 + half * 16)     = t0;
        *(short8*)(Vt + (size_t)d * NTOT + n0 + half * 16 + 8) = t1;
    } else {
        f32x4 z = {0.f, 0.f, 0.f, 0.f};
        float* dst = outz + (size_t)(bid - 640) * 4096;
        #pragma unroll
        for (int j = 0; j < 4; ++j)
            *(f32x4*)(dst + (size_t)(tid + 256 * j) * 4) = z;
    }
}

// ---------------- main: block = n-tile(128) x m-chunk(512) ----------------
// grid = 1024 (mc*32 + nb, nb fast => same-mc cohort concurrent), 256 thr.
__global__ __launch_bounds__(256) void tide_main(
    const short* __restrict__ Xb, const float* __restrict__ x2g,
    const short* __restrict__ Pb, const float* __restrict__ p2g,
    const float* __restrict__ cg, const short* __restrict__ Vt,
    float* __restrict__ rsum_g, float* __restrict__ oaccum)
{
    __shared__ __attribute__((aligned(16))) short lds_xbuf[2][16 * DD];  // 8 KB
    __shared__ __attribute__((aligned(16))) float lds_x2[512];           // 2 KB
    __shared__ float lds_rs[4][16];
    __shared__ float lds_rsall[512];                                     // 2 KB
    __shared__ int   lds_flag[4];
    __shared__ __attribute__((aligned(16))) short lds_w[4][16 * 32];     // 4 KB

    const int tid = threadIdx.x;
    const int wid = tid >> 6, lane = tid & 63;
    const int lo = lane & 15, hi = lane >> 4;
    const int nb = blockIdx.x & 31, mc = blockIdx.x >> 5;
    const int m0g = mc * 512;
    const int ns0 = nb * 128 + wid * 32;   // wave's n-base (32 cols)

    // ---- loop-invariant P fragments in registers ----
    // B-frag 16x16x32: lane holds P[n=base+lo][k=(kf*4+hi)*8 + j]
    short8 pf0[4], pf1[4];
    #pragma unroll
    for (int kf = 0; kf < 4; ++kf) {
        pf0[kf] = *(const short8*)(Pb + (size_t)(ns0 + lo) * DD + (kf * 4 + hi) * 8);
        pf1[kf] = *(const short8*)(Pb + (size_t)(ns0 + 16 + lo) * DD + (kf * 4 + hi) * 8);
    }
    const float p2v0 = p2g[ns0 + lo], p2v1 = p2g[ns0 + 16 + lo];
    const float cv0  = cg[ns0 + lo],  cv1  = cg[ns0 + 16 + lo];

    // x2 chunk -> LDS (once)
    lds_x2[tid]       = x2g[m0g + tid];
    lds_x2[tid + 256] = x2g[m0g + tid + 256];

    // stage subtile 0 (pre-swizzled source, linear LDS dest)
    const int srow = tid >> 4;
    const int sch  = (tid & 15) ^ (srow & 7);
    const short* xsrc = Xb + (size_t)(m0g + srow) * DD + sch * 8;
    __builtin_amdgcn_global_load_lds(
        (const __attribute__((address_space(1))) void*)xsrc,
        (__attribute__((address_space(3))) void*)((short*)lds_xbuf + tid * 8),
        16, 0, 0);
    __syncthreads();  // drains vmcnt; x2 ready

    for (int t = 0; t < 32; ++t) {
        // ---- prefetch next subtile ----
        if (t < 31) {
            __builtin_amdgcn_global_load_lds(
                (const __attribute__((address_space(1))) void*)(xsrc + (t + 1) * 2048),
                (__attribute__((address_space(3))) void*)
                    ((short*)lds_xbuf + ((t + 1) & 1) * 2048 + tid * 8),
                16, 0, 0);
            asm volatile("s_waitcnt vmcnt(1)" ::: "memory");
        } else {
            asm volatile("s_waitcnt vmcnt(0)" ::: "memory");
        }
        __builtin_amdgcn_sched_barrier(0);
        __builtin_amdgcn_s_barrier();     // #1: current buffer staged by all waves
        __builtin_amdgcn_sched_barrier(0);

        f32x4 x2r = *(const f32x4*)(lds_x2 + t * 16 + hi * 4);

        // A-frags from swizzled LDS: X[m=lo][k=(kf*4+hi)*8+j]
        const short* xb = (const short*)lds_xbuf + (t & 1) * 2048;
        short8 xf[4];
        #pragma unroll
        for (int kf = 0; kf < 4; ++kf) {
            int q = kf * 4 + hi;
            xf[kf] = *(const short8*)(xb + lo * DD + ((q ^ (lo & 7)) * 8));
        }
        f32x4 s0 = {0.f,0.f,0.f,0.f}, s1 = {0.f,0.f,0.f,0.f};
        #pragma unroll
        for (int kf = 0; kf < 4; ++kf) {
            s0 = __builtin_amdgcn_mfma_f32_16x16x32_bf16(xf[kf], pf0[kf], s0, 0, 0, 0);
            s1 = __builtin_amdgcn_mfma_f32_16x16x32_bf16(xf[kf], pf1[kf], s1, 0, 0, 0);
        }

        // pointwise: C row m=hi*4+r, cols ns0+lo / ns0+16+lo
        float w[8], vsum[4], wmax = 0.f;
        #pragma unroll
        for (int r = 0; r < 4; ++r) {
            float d2a = fmaf(s0[r], -2.f, x2r[r] + p2v0);
            float d2b = fmaf(s1[r], -2.f, x2r[r] + p2v1);
            d2a = fmaxf(d2a, 0.f); d2b = fmaxf(d2b, 0.f);
            float wa = exp2f(__builtin_amdgcn_sqrtf(d2a) * cv0);
            float wb = exp2f(__builtin_amdgcn_sqrtf(d2b) * cv1);
            w[r] = wa; w[4 + r] = wb;
            wmax = fmaxf(wmax, fmaxf(wa, wb));
            vsum[r] = wa + wb;
        }
        #pragma unroll
        for (int r = 0; r < 4; ++r) {
            float v = vsum[r];
            v += __shfl_xor(v, 1); v += __shfl_xor(v, 2);
            v += __shfl_xor(v, 4); v += __shfl_xor(v, 8);
            if (lo == 0) lds_rs[wid][hi * 4 + r] = v;
        }
        int anyw = __any(wmax > 0.f);
        if (lane == 0) lds_flag[wid] = anyw;
        asm volatile("s_waitcnt lgkmcnt(0)" ::: "memory");
        __builtin_amdgcn_s_barrier();     // #2: lds_rs/flag visible; buf reads done
        __builtin_amdgcn_sched_barrier(0);

        if (wid == 0 && lane < 16) {  // cross-wave rsum -> per-block LDS table
            lds_rsall[t * 16 + lane] = lds_rs[0][lane] + lds_rs[1][lane]
                                     + lds_rs[2][lane] + lds_rs[3][lane];
        }
        if (lds_flag[0] | lds_flag[1] | lds_flag[2] | lds_flag[3]) {
            // exact PV path (wave-private W redistribute; never taken here)
            #pragma unroll
            for (int r = 0; r < 4; ++r) {
                lds_w[wid][(hi * 4 + r) * 32 + lo]      = f2bf(w[r]);
                lds_w[wid][(hi * 4 + r) * 32 + 16 + lo] = f2bf(w[4 + r]);
            }
            // same-wave write->read; compiler inserts lgkmcnt
            short8 wfr = *(const short8*)(&lds_w[wid][lo * 32 + hi * 8]);
            #pragma unroll
            for (int df = 0; df < 8; ++df) {
                short8 vf = *(const short8*)(Vt + (size_t)(df * 16 + lo) * NTOT + ns0 + hi * 8);
                f32x4 of = {0.f,0.f,0.f,0.f};
                of = __builtin_amdgcn_mfma_f32_16x16x32_bf16(wfr, vf, of, 0, 0, 0);
                #pragma unroll
                for (int r = 0; r < 4; ++r)
                    atomicAdd(&oaccum[(size_t)(m0g + t * 16 + hi * 4 + r) * DD + df * 16 + lo],
                              of[r]);
            }
        }
    }

    __syncthreads();
    for (int i = tid; i < 512; i += 256)
        rsum_g[(size_t)(m0g + i) * 32 + nb] = lds_rsall[i];
}

// ---------------- normalize: out = oaccum / (sum_nb rsum + 1e-8) ----------
__global__ __launch_bounds__(256) void tide_norm(
    const float* __restrict__ rsum_g, float* __restrict__ outp)
{
    const int g = blockIdx.x * 256 + threadIdx.x;
    const int row = g >> 5, c = g & 31;
    float s = rsum_g[(size_t)row * 32 + c];
    #pragma unroll
    for (int o = 1; o < 32; o <<= 1) s += __shfl_xor(s, o, 32);
    const float inv = 1.f / (s + 1e-8f);
    f32x4 o4 = *(const f32x4*)(outp + (size_t)g * 4);
    o4[0] *= inv; o4[1] *= inv; o4[2] *= inv; o4[3] *= inv;
    *(f32x4*)(outp + (size_t)g * 4) = o4;
}

extern "C" void kernel_launch(void* const* d_in, const int* in_sizes, int n_in,
                              void* d_out, int out_size, void* d_ws, size_t ws_size,
                              hipStream_t stream) {
    const float* x    = (const float*)d_in[0];  // [8,2048,128]
    const float* pos  = (const float*)d_in[1];  // [4096,128]
    const float* val  = (const float*)d_in[2];  // [4096,128]
    const float* temp = (const float*)d_in[3];  // [4096]
    float* out = (float*)d_out;

    char* ws = (char*)d_ws;
    short* Xb     = (short*)(ws);                    // 4 MB
    short* Pb     = (short*)(ws + 4194304);          // 1 MB
    short* Vt     = (short*)(ws + 5242880);          // 1 MB
    float* x2g    = (float*)(ws + 6291456);          // 64 KB
    float* p2g    = (float*)(ws + 6356992);          // 16 KB
    float* cg     = (float*)(ws + 6373376);          // 16 KB
    float* rsum_g = (float*)(ws + 6389760);          // 2 MB (ends ~8.1 MB)

    hipLaunchKernelGGL(tide_prep, dim3(1152), dim3(256), 0, stream,
                       x, pos, val, temp, Xb, x2g, Pb, p2g, cg, Vt, out);
    hipLaunchKernelGGL(tide_main, dim3(1024), dim3(256), 0, stream,
                       Xb, x2g, Pb, p2g, cg, Vt, rsum_g, out);
    hipLaunchKernelGGL(tide_norm, dim3(2048), dim3(256), 0, stream,
                       rsum_g, out);
}